// Round 3
// baseline (4966.845 us; speedup 1.0000x reference)
//
#include <hip/hip_runtime.h>

#define HDIM 64
#define KDIM 128
#define NGRAPH 16

__device__ __forceinline__ float warp_sum64(float v) {
#pragma unroll
    for (int off = 32; off >= 1; off >>= 1) v += __shfl_xor(v, off, 64);
    return v;
}

// ---------------------------------------------------------------------------
// Edge kernel: msg = relu(concat(h[src], ee[e]) @ W + b); pooled[tgt] += msg
// One wave processes 4 edges at a time. Weight column j lives in lane j's
// registers (128 VGPRs). Per-edge inputs staged in a per-wave LDS region and
// consumed via broadcast float4 reads (same-address ds_read = conflict-free).
// ---------------------------------------------------------------------------
__launch_bounds__(256)
__global__ void edge_msg_scatter(const float* __restrict__ htab,
                                 const float* __restrict__ ee,
                                 const int* __restrict__ esrc,
                                 const int* __restrict__ etgt,
                                 const float* __restrict__ W,    // [128][64]
                                 const float* __restrict__ bias, // [64]
                                 float* __restrict__ pooled,     // [N][64]
                                 int E, int iters)
{
    const int lane  = threadIdx.x & 63;
    const int wslot = threadIdx.x >> 6;          // 0..3
    const int wid   = blockIdx.x * 4 + wslot;
    const int nw    = gridDim.x * 4;

    float wreg[KDIM];
#pragma unroll
    for (int k = 0; k < KDIM; ++k) wreg[k] = W[k * HDIM + lane];
    const float bj = bias[lane];

    __shared__ float in_lds[4][4][KDIM];

    for (int it = 0; it < iters; ++it) {
        const int e0 = (wid + it * nw) * 4;
        __syncthreads();   // uniform trip count for all waves in block
#pragma unroll
        for (int e = 0; e < 4; ++e) {
            int eu = e0 + e;
            if (eu < E) {
                eu = __builtin_amdgcn_readfirstlane(eu);
                const int src = esrc[eu];
                in_lds[wslot][e][lane]        = htab[src * HDIM + lane];
                in_lds[wslot][e][HDIM + lane] = ee[(size_t)eu * HDIM + lane];
            }
        }
        __syncthreads();
        if (e0 < E) {
            float acc0 = 0.f, acc1 = 0.f, acc2 = 0.f, acc3 = 0.f;
#pragma unroll
            for (int k4 = 0; k4 < KDIM / 4; ++k4) {
                const float4 i0 = *reinterpret_cast<const float4*>(&in_lds[wslot][0][k4 * 4]);
                const float4 i1 = *reinterpret_cast<const float4*>(&in_lds[wslot][1][k4 * 4]);
                const float4 i2 = *reinterpret_cast<const float4*>(&in_lds[wslot][2][k4 * 4]);
                const float4 i3 = *reinterpret_cast<const float4*>(&in_lds[wslot][3][k4 * 4]);
                acc0 = fmaf(i0.x, wreg[k4*4+0], acc0);
                acc1 = fmaf(i1.x, wreg[k4*4+0], acc1);
                acc2 = fmaf(i2.x, wreg[k4*4+0], acc2);
                acc3 = fmaf(i3.x, wreg[k4*4+0], acc3);
                acc0 = fmaf(i0.y, wreg[k4*4+1], acc0);
                acc1 = fmaf(i1.y, wreg[k4*4+1], acc1);
                acc2 = fmaf(i2.y, wreg[k4*4+1], acc2);
                acc3 = fmaf(i3.y, wreg[k4*4+1], acc3);
                acc0 = fmaf(i0.z, wreg[k4*4+2], acc0);
                acc1 = fmaf(i1.z, wreg[k4*4+2], acc1);
                acc2 = fmaf(i2.z, wreg[k4*4+2], acc2);
                acc3 = fmaf(i3.z, wreg[k4*4+2], acc3);
                acc0 = fmaf(i0.w, wreg[k4*4+3], acc0);
                acc1 = fmaf(i1.w, wreg[k4*4+3], acc1);
                acc2 = fmaf(i2.w, wreg[k4*4+3], acc2);
                acc3 = fmaf(i3.w, wreg[k4*4+3], acc3);
            }
            const float accs[4] = {acc0, acc1, acc2, acc3};
#pragma unroll
            for (int e = 0; e < 4; ++e) {
                const int eu = e0 + e;
                if (eu < E) {
                    const int tgt = etgt[__builtin_amdgcn_readfirstlane(eu)];
                    float m = accs[e] + bj;
                    m = m > 0.f ? m : 0.f;
                    atomicAdd(&pooled[(size_t)tgt * HDIM + lane], m);
                }
            }
        }
    }
}

// ---------------------------------------------------------------------------
// Node kernel: h = LN(relu(h + concat(h, pooled) @ Wr + br))
// One wave per node; inputs broadcast via __shfl (no LDS needed).
// ---------------------------------------------------------------------------
__launch_bounds__(256)
__global__ void node_update(const float* __restrict__ hin,
                            const float* __restrict__ pooled,
                            const float* __restrict__ W,
                            const float* __restrict__ bias,
                            const float* __restrict__ gamma,
                            const float* __restrict__ beta,
                            float* __restrict__ hout,
                            int N)
{
    const int lane = threadIdx.x & 63;
    const int wid  = blockIdx.x * 4 + (threadIdx.x >> 6);
    const int nw   = gridDim.x * 4;

    float wreg[KDIM];
#pragma unroll
    for (int k = 0; k < KDIM; ++k) wreg[k] = W[k * HDIM + lane];
    const float bj  = bias[lane];
    const float gj  = gamma[lane];
    const float btj = beta[lane];

    for (int n = wid; n < N; n += nw) {
        const float va = hin[(size_t)n * HDIM + lane];
        const float vb = pooled[(size_t)n * HDIM + lane];
        float a0 = 0.f, a1 = 0.f, a2 = 0.f, a3 = 0.f;
#pragma unroll
        for (int k = 0; k < HDIM; k += 4) {
            a0 = fmaf(__shfl(va, k + 0, 64), wreg[k + 0], a0);
            a1 = fmaf(__shfl(va, k + 1, 64), wreg[k + 1], a1);
            a2 = fmaf(__shfl(va, k + 2, 64), wreg[k + 2], a2);
            a3 = fmaf(__shfl(va, k + 3, 64), wreg[k + 3], a3);
        }
#pragma unroll
        for (int k = 0; k < HDIM; k += 4) {
            a0 = fmaf(__shfl(vb, k + 0, 64), wreg[HDIM + k + 0], a0);
            a1 = fmaf(__shfl(vb, k + 1, 64), wreg[HDIM + k + 1], a1);
            a2 = fmaf(__shfl(vb, k + 2, 64), wreg[HDIM + k + 2], a2);
            a3 = fmaf(__shfl(vb, k + 3, 64), wreg[HDIM + k + 3], a3);
        }
        float x = va + ((a0 + a1) + (a2 + a3)) + bj;
        x = x > 0.f ? x : 0.f;
        const float mean = warp_sum64(x) * (1.0f / HDIM);
        const float d = x - mean;
        const float var = warp_sum64(d * d) * (1.0f / HDIM);
        const float y = d * rsqrtf(var + 1e-3f) * gj + btj;
        hout[(size_t)n * HDIM + lane] = y;
    }
}

// ---------------------------------------------------------------------------
// Per-graph mean pooling: block-local LDS accumulation, then global atomics.
// ---------------------------------------------------------------------------
__launch_bounds__(256)
__global__ void graph_pool(const float* __restrict__ h,
                           const int* __restrict__ gid,
                           float* __restrict__ sums,   // [16][64]
                           float* __restrict__ cnts,   // [16]
                           int N)
{
    __shared__ float ls[NGRAPH * HDIM];
    __shared__ float lc[NGRAPH];
    for (int i = threadIdx.x; i < NGRAPH * HDIM; i += blockDim.x) ls[i] = 0.f;
    if (threadIdx.x < NGRAPH) lc[threadIdx.x] = 0.f;
    __syncthreads();

    const int lane = threadIdx.x & 63;
    const int wid  = blockIdx.x * 4 + (threadIdx.x >> 6);
    const int nw   = gridDim.x * 4;
    for (int n = wid; n < N; n += nw) {
        const int g = __builtin_amdgcn_readfirstlane(gid[n]);
        atomicAdd(&ls[g * HDIM + lane], h[(size_t)n * HDIM + lane]);
        if (lane == 0) atomicAdd(&lc[g], 1.0f);
    }
    __syncthreads();
    for (int i = threadIdx.x; i < NGRAPH * HDIM; i += blockDim.x)
        if (ls[i] != 0.f) atomicAdd(&sums[i], ls[i]);
    if (threadIdx.x < NGRAPH && lc[threadIdx.x] != 0.f)
        atomicAdd(&cnts[threadIdx.x], lc[threadIdx.x]);
}

__global__ void finalize(const float* __restrict__ sums,
                         const float* __restrict__ cnts,
                         float* __restrict__ out)
{
    const int i = threadIdx.x;             // 1024 threads
    out[i] = sums[i] / fmaxf(cnts[i >> 6], 1.0f);
}

extern "C" void kernel_launch(void* const* d_in, const int* in_sizes, int n_in,
                              void* d_out, int out_size, void* d_ws, size_t ws_size,
                              hipStream_t stream)
{
    const float* hidden = (const float*)d_in[0];
    const float* ee     = (const float*)d_in[1];
    const int*   esrc   = (const int*)d_in[2];
    const int*   etgt   = (const int*)d_in[3];
    const int*   gid    = (const int*)d_in[4];
    const float* Wm     = (const float*)d_in[5];
    const float* bm     = (const float*)d_in[6];
    const float* Wr     = (const float*)d_in[7];
    const float* br     = (const float*)d_in[8];
    const float* gamma  = (const float*)d_in[9];
    const float* beta   = (const float*)d_in[10];

    const int N    = in_sizes[4];
    const int E    = in_sizes[2];
    const int hops = in_sizes[5] / (KDIM * HDIM);

    float* h_cur  = (float*)d_ws;                    // [N][64]
    float* pooled = h_cur + (size_t)N * HDIM;        // [N][64]
    float* sums   = pooled + (size_t)N * HDIM;       // [16][64]
    float* cnts   = sums + NGRAPH * HDIM;            // [16]

    const int eblocks = 2048;
    const int chunks  = (E + 3) / 4;
    const int iters   = (chunks + eblocks * 4 - 1) / (eblocks * 4);

    const float* hin = hidden;
    for (int i = 0; i < hops; ++i) {
        hipMemsetAsync(pooled, 0, (size_t)N * HDIM * sizeof(float), stream);
        edge_msg_scatter<<<eblocks, 256, 0, stream>>>(
            hin, ee, esrc, etgt,
            Wm + (size_t)i * KDIM * HDIM, bm + (size_t)i * HDIM,
            pooled, E, iters);
        node_update<<<1024, 256, 0, stream>>>(
            hin, pooled,
            Wr + (size_t)i * KDIM * HDIM, br + (size_t)i * HDIM,
            gamma, beta, h_cur, N);
        hin = h_cur;
    }
    hipMemsetAsync(sums, 0, (NGRAPH * HDIM + NGRAPH) * sizeof(float), stream);
    graph_pool<<<512, 256, 0, stream>>>(h_cur, gid, sums, cnts, N);
    finalize<<<1, 1024, 0, stream>>>(sums, cnts, (float*)d_out);
}

// Round 5
// 1230.065 us; speedup vs baseline: 4.0379x; 4.0379x over previous
//
#include <hip/hip_runtime.h>

#define HDIM 64
#define NGRAPH 16

typedef __attribute__((ext_vector_type(8))) short bf16x8;
typedef __attribute__((ext_vector_type(4))) float f32x4;

__device__ __forceinline__ unsigned short f2bf(float f) {
    unsigned u = __float_as_uint(f);
    u += 0x7fffu + ((u >> 16) & 1u);     // round-to-nearest-even
    return (unsigned short)(u >> 16);
}

// ---------------------------------------------------------------------------
// cast helpers (run once per launch)
// ---------------------------------------------------------------------------
__global__ void cast_f32_bf16(const float* __restrict__ in,
                              unsigned short* __restrict__ out, long n)
{
    long i = ((long)blockIdx.x * blockDim.x + threadIdx.x) * 4;
    const long stride = (long)gridDim.x * blockDim.x * 4;
    for (; i + 3 < n; i += stride) {
        const float4 v = *reinterpret_cast<const float4*>(in + i);
        ushort4 o;
        o.x = f2bf(v.x); o.y = f2bf(v.y); o.z = f2bf(v.z); o.w = f2bf(v.w);
        *reinterpret_cast<ushort4*>(out + i) = o;
    }
}

__global__ void cast_w(const float* __restrict__ wm, const float* __restrict__ wr,
                       unsigned short* __restrict__ wmb, unsigned short* __restrict__ wrb,
                       int n)
{
    const int i = blockIdx.x * blockDim.x + threadIdx.x;
    if (i < n) { wmb[i] = f2bf(wm[i]); wrb[i] = f2bf(wr[i]); }
}

// ---------------------------------------------------------------------------
// Edge kernel (MFMA): one wave = 16 edges. A = concat(h[src], ee[e]) [16x128]
// bf16, B = W [128x64] bf16 held as loop-invariant register fragments.
// No LDS, no barriers -> waves fully independent (fixes the r3 latency stall).
// MFMA layouts (m89-verified): A: row=lane&15, k=(lane>>4)*8+j. B: symmetric.
// C/D: col=lane&15, row=(lane>>4)*4+reg.
// ---------------------------------------------------------------------------
__launch_bounds__(256)
__global__ void edge_mfma(const unsigned short* __restrict__ hb,   // [N][64] bf16
                          const float* __restrict__ ee,            // [E][64] f32
                          const int* __restrict__ esrc,
                          const int* __restrict__ etgt,
                          const unsigned short* __restrict__ Wbf,  // [128][64] bf16
                          const float* __restrict__ bias,          // [64]
                          float* __restrict__ pooled,              // [N][64]
                          int ngrp, int E)
{
    const int lane = threadIdx.x & 63;
    const int col  = lane & 15;
    const int krow = (lane >> 4) * 8;
    const int wid  = blockIdx.x * 4 + (threadIdx.x >> 6);
    const int nw   = gridDim.x * 4;

    bf16x8 bfrag[4][4];
#pragma unroll
    for (int t = 0; t < 4; ++t)
#pragma unroll
        for (int ks = 0; ks < 4; ++ks)
#pragma unroll
            for (int j = 0; j < 8; ++j)
                bfrag[t][ks][j] = (short)Wbf[(ks * 32 + krow + j) * HDIM + t * 16 + col];

    float bias_t[4];
#pragma unroll
    for (int t = 0; t < 4; ++t) bias_t[t] = bias[t * 16 + col];

    for (int g = wid; g < ngrp; g += nw) {
        const int e0     = g * 16;
        const int myedge = min(e0 + col, E - 1);
        const int src    = esrc[myedge];
        const int tgt    = etgt[myedge];

        // A fragments: k<64 from bf16 h table, k>=64 from f32 ee (inline cvt)
        const unsigned short* hrow = hb + (size_t)src * HDIM;
        const bf16x8 a0 = *reinterpret_cast<const bf16x8*>(hrow + krow);
        const bf16x8 a1 = *reinterpret_cast<const bf16x8*>(hrow + 32 + krow);

        const float* erow = ee + (size_t)myedge * HDIM;
        const float4 e0v = *reinterpret_cast<const float4*>(erow + krow);
        const float4 e1v = *reinterpret_cast<const float4*>(erow + krow + 4);
        const float4 e2v = *reinterpret_cast<const float4*>(erow + 32 + krow);
        const float4 e3v = *reinterpret_cast<const float4*>(erow + 32 + krow + 4);
        bf16x8 a2, a3;
        a2[0] = (short)f2bf(e0v.x); a2[1] = (short)f2bf(e0v.y);
        a2[2] = (short)f2bf(e0v.z); a2[3] = (short)f2bf(e0v.w);
        a2[4] = (short)f2bf(e1v.x); a2[5] = (short)f2bf(e1v.y);
        a2[6] = (short)f2bf(e1v.z); a2[7] = (short)f2bf(e1v.w);
        a3[0] = (short)f2bf(e2v.x); a3[1] = (short)f2bf(e2v.y);
        a3[2] = (short)f2bf(e2v.z); a3[3] = (short)f2bf(e2v.w);
        a3[4] = (short)f2bf(e3v.x); a3[5] = (short)f2bf(e3v.y);
        a3[6] = (short)f2bf(e3v.z); a3[7] = (short)f2bf(e3v.w);

        f32x4 acc[4] = {{0.f,0.f,0.f,0.f},{0.f,0.f,0.f,0.f},
                        {0.f,0.f,0.f,0.f},{0.f,0.f,0.f,0.f}};
#pragma unroll
        for (int t = 0; t < 4; ++t) {
            acc[t] = __builtin_amdgcn_mfma_f32_16x16x32_bf16(a0, bfrag[t][0], acc[t], 0, 0, 0);
            acc[t] = __builtin_amdgcn_mfma_f32_16x16x32_bf16(a1, bfrag[t][1], acc[t], 0, 0, 0);
            acc[t] = __builtin_amdgcn_mfma_f32_16x16x32_bf16(a2, bfrag[t][2], acc[t], 0, 0, 0);
            acc[t] = __builtin_amdgcn_mfma_f32_16x16x32_bf16(a3, bfrag[t][3], acc[t], 0, 0, 0);
        }

        int  tg[4];
        bool vld[4];
#pragma unroll
        for (int r = 0; r < 4; ++r) {
            const int row = (lane >> 4) * 4 + r;
            tg[r]  = __shfl(tgt, row, 64);
            vld[r] = (e0 + row) < E;
        }
#pragma unroll
        for (int r = 0; r < 4; ++r) {
            if (vld[r]) {
#pragma unroll
                for (int t = 0; t < 4; ++t) {
                    const float v = fmaxf(acc[t][r] + bias_t[t], 0.f);
                    atomicAdd(pooled + (size_t)tg[r] * HDIM + t * 16 + col, v);
                }
            }
        }
    }
}

// ---------------------------------------------------------------------------
// Node kernel (MFMA): one wave = 16 nodes. dense = concat(h, pooled) @ Wr,
// x = relu(h_f32 + dense + b), then fused LayerNorm in C-layout:
// row r's 64 cols live in one 16-lane group (4 tiles x 16 lanes), stats via
// shfl_xor {1,2,4,8}. Writes f32 h and its bf16 shadow for the next hop.
// ---------------------------------------------------------------------------
__launch_bounds__(256)
__global__ void node_mfma(const float* __restrict__ hres,           // [N][64] f32 residual in
                          const unsigned short* __restrict__ hbin,  // [N][64] bf16
                          const float* __restrict__ pooled,         // [N][64] f32
                          const unsigned short* __restrict__ Wbf,   // [128][64] bf16
                          const float* __restrict__ bias,
                          const float* __restrict__ gamma,
                          const float* __restrict__ beta,
                          float* __restrict__ hout,
                          unsigned short* __restrict__ hbout,
                          int ngrp, int N)
{
    const int lane = threadIdx.x & 63;
    const int col  = lane & 15;
    const int krow = (lane >> 4) * 8;
    const int wid  = blockIdx.x * 4 + (threadIdx.x >> 6);
    const int nw   = gridDim.x * 4;

    bf16x8 bfrag[4][4];
#pragma unroll
    for (int t = 0; t < 4; ++t)
#pragma unroll
        for (int ks = 0; ks < 4; ++ks)
#pragma unroll
            for (int j = 0; j < 8; ++j)
                bfrag[t][ks][j] = (short)Wbf[(ks * 32 + krow + j) * HDIM + t * 16 + col];

    float bias_t[4], gam_t[4], bet_t[4];
#pragma unroll
    for (int t = 0; t < 4; ++t) {
        bias_t[t] = bias[t * 16 + col];
        gam_t[t]  = gamma[t * 16 + col];
        bet_t[t]  = beta[t * 16 + col];
    }

    for (int g = wid; g < ngrp; g += nw) {
        const int n0  = g * 16;
        const int myn = min(n0 + col, N - 1);

        const unsigned short* hrow = hbin + (size_t)myn * HDIM;
        const bf16x8 a0 = *reinterpret_cast<const bf16x8*>(hrow + krow);
        const bf16x8 a1 = *reinterpret_cast<const bf16x8*>(hrow + 32 + krow);

        const float* prow = pooled + (size_t)myn * HDIM;
        const float4 p0v = *reinterpret_cast<const float4*>(prow + krow);
        const float4 p1v = *reinterpret_cast<const float4*>(prow + krow + 4);
        const float4 p2v = *reinterpret_cast<const float4*>(prow + 32 + krow);
        const float4 p3v = *reinterpret_cast<const float4*>(prow + 32 + krow + 4);
        bf16x8 a2, a3;
        a2[0] = (short)f2bf(p0v.x); a2[1] = (short)f2bf(p0v.y);
        a2[2] = (short)f2bf(p0v.z); a2[3] = (short)f2bf(p0v.w);
        a2[4] = (short)f2bf(p1v.x); a2[5] = (short)f2bf(p1v.y);
        a2[6] = (short)f2bf(p1v.z); a2[7] = (short)f2bf(p1v.w);
        a3[0] = (short)f2bf(p2v.x); a3[1] = (short)f2bf(p2v.y);
        a3[2] = (short)f2bf(p2v.z); a3[3] = (short)f2bf(p2v.w);
        a3[4] = (short)f2bf(p3v.x); a3[5] = (short)f2bf(p3v.y);
        a3[6] = (short)f2bf(p3v.z); a3[7] = (short)f2bf(p3v.w);

        f32x4 acc[4] = {{0.f,0.f,0.f,0.f},{0.f,0.f,0.f,0.f},
                        {0.f,0.f,0.f,0.f},{0.f,0.f,0.f,0.f}};
#pragma unroll
        for (int t = 0; t < 4; ++t) {
            acc[t] = __builtin_amdgcn_mfma_f32_16x16x32_bf16(a0, bfrag[t][0], acc[t], 0, 0, 0);
            acc[t] = __builtin_amdgcn_mfma_f32_16x16x32_bf16(a1, bfrag[t][1], acc[t], 0, 0, 0);
            acc[t] = __builtin_amdgcn_mfma_f32_16x16x32_bf16(a2, bfrag[t][2], acc[t], 0, 0, 0);
            acc[t] = __builtin_amdgcn_mfma_f32_16x16x32_bf16(a3, bfrag[t][3], acc[t], 0, 0, 0);
        }

        // epilogue: residual + bias + relu, then LN per row
        float xv[4][4], s1r[4], s2r[4];
#pragma unroll
        for (int r = 0; r < 4; ++r) {
            const int row = (lane >> 4) * 4 + r;
            const int nc  = min(n0 + row, N - 1);
            s1r[r] = 0.f; s2r[r] = 0.f;
#pragma unroll
            for (int t = 0; t < 4; ++t) {
                const float va = hres[(size_t)nc * HDIM + t * 16 + col];
                float x = fmaxf(va + acc[t][r] + bias_t[t], 0.f);
                xv[t][r] = x;
                s1r[r] += x;
                s2r[r] += x * x;
            }
        }
#pragma unroll
        for (int off = 1; off < 16; off <<= 1) {
#pragma unroll
            for (int r = 0; r < 4; ++r) {
                s1r[r] += __shfl_xor(s1r[r], off, 64);
                s2r[r] += __shfl_xor(s2r[r], off, 64);
            }
        }
#pragma unroll
        for (int r = 0; r < 4; ++r) {
            const int row = (lane >> 4) * 4 + r;
            const int n   = n0 + row;
            const float mean = s1r[r] * (1.0f / HDIM);
            const float var  = s2r[r] * (1.0f / HDIM) - mean * mean;
            const float inv  = rsqrtf(var + 1e-3f);
            if (n < N) {
#pragma unroll
                for (int t = 0; t < 4; ++t) {
                    const float y = (xv[t][r] - mean) * inv * gam_t[t] + bet_t[t];
                    hout[(size_t)n * HDIM + t * 16 + col]  = y;
                    hbout[(size_t)n * HDIM + t * 16 + col] = f2bf(y);
                }
            }
        }
    }
}

// ---------------------------------------------------------------------------
// Per-graph mean pooling (unchanged from r3)
// ---------------------------------------------------------------------------
__launch_bounds__(256)
__global__ void graph_pool(const float* __restrict__ h,
                           const int* __restrict__ gid,
                           float* __restrict__ sums,
                           float* __restrict__ cnts,
                           int N)
{
    __shared__ float ls[NGRAPH * HDIM];
    __shared__ float lc[NGRAPH];
    for (int i = threadIdx.x; i < NGRAPH * HDIM; i += blockDim.x) ls[i] = 0.f;
    if (threadIdx.x < NGRAPH) lc[threadIdx.x] = 0.f;
    __syncthreads();

    const int lane = threadIdx.x & 63;
    const int wid  = blockIdx.x * 4 + (threadIdx.x >> 6);
    const int nw   = gridDim.x * 4;
    for (int n = wid; n < N; n += nw) {
        const int g = __builtin_amdgcn_readfirstlane(gid[n]);
        atomicAdd(&ls[g * HDIM + lane], h[(size_t)n * HDIM + lane]);
        if (lane == 0) atomicAdd(&lc[g], 1.0f);
    }
    __syncthreads();
    for (int i = threadIdx.x; i < NGRAPH * HDIM; i += blockDim.x)
        if (ls[i] != 0.f) atomicAdd(&sums[i], ls[i]);
    if (threadIdx.x < NGRAPH && lc[threadIdx.x] != 0.f)
        atomicAdd(&cnts[threadIdx.x], lc[threadIdx.x]);
}

__global__ void finalize(const float* __restrict__ sums,
                         const float* __restrict__ cnts,
                         float* __restrict__ out)
{
    const int i = threadIdx.x;
    out[i] = sums[i] / fmaxf(cnts[i >> 6], 1.0f);
}

extern "C" void kernel_launch(void* const* d_in, const int* in_sizes, int n_in,
                              void* d_out, int out_size, void* d_ws, size_t ws_size,
                              hipStream_t stream)
{
    const float* hidden = (const float*)d_in[0];
    const float* ee     = (const float*)d_in[1];
    const int*   esrc   = (const int*)d_in[2];
    const int*   etgt   = (const int*)d_in[3];
    const int*   gid    = (const int*)d_in[4];
    const float* Wm     = (const float*)d_in[5];
    const float* bm     = (const float*)d_in[6];
    const float* Wr     = (const float*)d_in[7];
    const float* br     = (const float*)d_in[8];
    const float* gamma  = (const float*)d_in[9];
    const float* beta   = (const float*)d_in[10];

    const int N    = in_sizes[4];
    const int E    = in_sizes[2];
    const int hops = in_sizes[5] / (128 * HDIM);

    // workspace layout (bytes): h f32 | pooled f32 | hb bf16 | Wm_bf | Wr_bf | sums | cnts
    float* h      = (float*)d_ws;                               // N*64 f32
    float* pooled = h + (size_t)N * HDIM;                       // N*64 f32
    unsigned short* hb  = (unsigned short*)(pooled + (size_t)N * HDIM); // N*64 bf16
    unsigned short* Wmb = hb + (size_t)N * HDIM;                // hops*8192 bf16
    unsigned short* Wrb = Wmb + (size_t)hops * 128 * HDIM;      // hops*8192 bf16
    float* sums = (float*)(Wrb + (size_t)hops * 128 * HDIM);    // 1024 f32
    float* cnts = sums + NGRAPH * HDIM;                         // 16 f32

    const int ngrpE = (E + 15) / 16;
    const int ngrpN = (N + 15) / 16;

    // one-time prep: bf16 shadows of h0 and weights
    cast_f32_bf16<<<2048, 256, 0, stream>>>(hidden, hb, (long)N * HDIM);
    const int wn = hops * 128 * HDIM;
    cast_w<<<(wn + 255) / 256, 256, 0, stream>>>(Wm, Wr, Wmb, Wrb, wn);

    const float* hres = hidden;
    for (int i = 0; i < hops; ++i) {
        hipMemsetAsync(pooled, 0, (size_t)N * HDIM * sizeof(float), stream);
        edge_mfma<<<2048, 256, 0, stream>>>(
            hb, ee, esrc, etgt,
            Wmb + (size_t)i * 128 * HDIM, bm + (size_t)i * HDIM,
            pooled, ngrpE, E);
        node_mfma<<<1024, 256, 0, stream>>>(
            hres, hb, pooled,
            Wrb + (size_t)i * 128 * HDIM, br + (size_t)i * HDIM,
            gamma, beta, h, hb, ngrpN, N);
        hres = h;   // next hop residual reads the f32 h we just wrote
    }

    hipMemsetAsync(sums, 0, (NGRAPH * HDIM + NGRAPH) * sizeof(float), stream);
    graph_pool<<<512, 256, 0, stream>>>(h, gid, sums, cnts, N);
    finalize<<<1, 1024, 0, stream>>>(sums, cnts, (float*)d_out);
}